// Round 1
// baseline (5831.343 us; speedup 1.0000x reference)
//
#include <hip/hip_runtime.h>
#include <math.h>

#define BT 64
#define CH 256
#define HW 4096
#define AL 32
#define SCALE 0.0625f   // 256^-0.5

__device__ __forceinline__ float gelu_f(float x){
    return 0.5f*x*(1.0f+erff(x*0.70710678118654752f));
}

// ---------------------------------------------------------------------------
// Pointwise conv over HW tokens: Out[b][o][p] = epi(sum_c W[o][c]*Xa[b][c][p]*(Xb?) + bias[o])
// 64x64 output tile per block, K-chunks of 16, 4x4 register blocking.
// EPI: 0=none, 1=gelu, 2=relu, 3=gate-combine: Out = E1 + tanh(v)*E2
template<int PREMUL, int EPI>
__global__ __launch_bounds__(256)
void conv_hw_kernel(const float* __restrict__ W, const float* __restrict__ bias,
                    const float* __restrict__ Xa, const float* __restrict__ Xb,
                    float* __restrict__ Out,
                    const float* __restrict__ E1, const float* __restrict__ E2)
{
    __shared__ float sW[16][64];
    __shared__ float sX[16][64];
    const int b  = blockIdx.z;
    const int o0 = blockIdx.y * 64;
    const int p0 = blockIdx.x * 64;
    const int tid = threadIdx.x;
    const int tx = tid & 15, ty = tid >> 4;
    const size_t xbase = (size_t)b*CH*HW;

    float acc[4][4] = {{0.f,0.f,0.f,0.f},{0.f,0.f,0.f,0.f},{0.f,0.f,0.f,0.f},{0.f,0.f,0.f,0.f}};

    const int w_oo = tid >> 2;
    const int w_kk = (tid & 3) * 4;
    const int x_kk = tid >> 4;
    const int x_pp = (tid & 15) * 4;

    for (int k0 = 0; k0 < CH; k0 += 16) {
        float4 w4 = *(const float4*)(W + (size_t)(o0 + w_oo)*CH + k0 + w_kk);
        float4 x4 = *(const float4*)(Xa + xbase + (size_t)(k0 + x_kk)*HW + p0 + x_pp);
        if (PREMUL) {
            float4 y4 = *(const float4*)(Xb + xbase + (size_t)(k0 + x_kk)*HW + p0 + x_pp);
            x4.x*=y4.x; x4.y*=y4.y; x4.z*=y4.z; x4.w*=y4.w;
        }
        sW[w_kk+0][w_oo]=w4.x; sW[w_kk+1][w_oo]=w4.y; sW[w_kk+2][w_oo]=w4.z; sW[w_kk+3][w_oo]=w4.w;
        *(float4*)&sX[x_kk][x_pp] = x4;
        __syncthreads();
        #pragma unroll
        for (int kk=0;kk<16;++kk){
            const float4 a = *(const float4*)&sW[kk][ty*4];
            const float4 v = *(const float4*)&sX[kk][tx*4];
            acc[0][0]+=a.x*v.x; acc[0][1]+=a.x*v.y; acc[0][2]+=a.x*v.z; acc[0][3]+=a.x*v.w;
            acc[1][0]+=a.y*v.x; acc[1][1]+=a.y*v.y; acc[1][2]+=a.y*v.z; acc[1][3]+=a.y*v.w;
            acc[2][0]+=a.z*v.x; acc[2][1]+=a.z*v.y; acc[2][2]+=a.z*v.z; acc[2][3]+=a.z*v.w;
            acc[3][0]+=a.w*v.x; acc[3][1]+=a.w*v.y; acc[3][2]+=a.w*v.z; acc[3][3]+=a.w*v.w;
        }
        __syncthreads();
    }
    #pragma unroll
    for (int i=0;i<4;++i){
        const int o = o0 + ty*4 + i;
        const float bv = bias ? bias[o] : 0.0f;
        float4 r;
        r.x = acc[i][0]+bv; r.y = acc[i][1]+bv; r.z = acc[i][2]+bv; r.w = acc[i][3]+bv;
        if (EPI==1){ r.x=gelu_f(r.x); r.y=gelu_f(r.y); r.z=gelu_f(r.z); r.w=gelu_f(r.w); }
        if (EPI==2){ r.x=fmaxf(r.x,0.f); r.y=fmaxf(r.y,0.f); r.z=fmaxf(r.z,0.f); r.w=fmaxf(r.w,0.f); }
        if (EPI==3){
            const float4 e1 = *(const float4*)(E1 + xbase + (size_t)o*HW + p0 + tx*4);
            const float4 e2 = *(const float4*)(E2 + xbase + (size_t)o*HW + p0 + tx*4);
            r.x = e1.x + tanhf(r.x)*e2.x;
            r.y = e1.y + tanhf(r.y)*e2.y;
            r.z = e1.z + tanhf(r.z)*e2.z;
            r.w = e1.w + tanhf(r.w)*e2.w;
        }
        *(float4*)(Out + xbase + (size_t)o*HW + p0 + tx*4) = r;
    }
}

// ---------------------------------------------------------------------------
// In-place InstanceNorm over HW per (b,c) row. blockIdx.x = b*CH + c.
__global__ __launch_bounds__(256)
void inorm_hw_kernel(float* __restrict__ Buf)
{
    const size_t base = (size_t)blockIdx.x * HW;
    const int tid = threadIdx.x;
    float4 v[4];
    float s=0.f, ss=0.f;
    #pragma unroll
    for (int i=0;i<4;++i){
        v[i] = *(const float4*)(Buf + base + tid*4 + i*1024);
        s  += v[i].x+v[i].y+v[i].z+v[i].w;
        ss += v[i].x*v[i].x + v[i].y*v[i].y + v[i].z*v[i].z + v[i].w*v[i].w;
    }
    #pragma unroll
    for (int off=1; off<64; off<<=1){
        s  += __shfl_xor(s, off);
        ss += __shfl_xor(ss, off);
    }
    __shared__ float rs[4], rss[4];
    if ((tid&63)==0){ rs[tid>>6]=s; rss[tid>>6]=ss; }
    __syncthreads();
    s  = rs[0]+rs[1]+rs[2]+rs[3];
    ss = rss[0]+rss[1]+rss[2]+rss[3];
    const float mean = s * (1.0f/HW);
    const float var  = ss * (1.0f/HW) - mean*mean;
    const float r = rsqrtf(var + 1e-5f);
    #pragma unroll
    for (int i=0;i<4;++i){
        float4 t;
        t.x=(v[i].x-mean)*r; t.y=(v[i].y-mean)*r; t.z=(v[i].z-mean)*r; t.w=(v[i].w-mean)*r;
        *(float4*)(Buf + base + tid*4 + i*1024) = t;
    }
}

// ---------------------------------------------------------------------------
// Pointwise conv over audio length L. EPI: 0=none, 1=*mask[b][l], 2=Resid + gelu(v)
template<int EPI>
__global__ __launch_bounds__(256)
void conv_l_kernel(const float* __restrict__ W, const float* __restrict__ bias,
                   const float* __restrict__ X, float* __restrict__ Out,
                   const float* __restrict__ Mask, const float* __restrict__ Resid)
{
    const int b = blockIdx.x;
    const int o = blockIdx.y*8 + (threadIdx.x>>5);
    const int l = threadIdx.x & 31;
    const float* xb = X + (size_t)b*CH*AL + l;
    const float* wr = W + (size_t)o*CH;
    float acc = bias ? bias[o] : 0.0f;
    #pragma unroll 8
    for (int c=0;c<CH;++c) acc = fmaf(wr[c], xb[(size_t)c*AL], acc);
    const size_t oi = (size_t)b*CH*AL + (size_t)o*AL + l;
    if (EPI==1) acc *= Mask[b*AL + l];
    if (EPI==2) acc = Resid[oi] + gelu_f(acc);
    Out[oi] = acc;
}

// ---------------------------------------------------------------------------
// Visual attention, fully fused per 64-token tile:
//   s[p][l] = scale * sum_c Q[b][c][p0+p]*K[b][c][l] + (10000*mask[l]-10000)
//   probs = softmax_l(s);  Out[b][c][p0+p] = sum_l probs[p][l]*AV[b][c][l]
__global__ __launch_bounds__(256)
void attn_v_kernel(const float* __restrict__ Q, const float* __restrict__ K,
                   const float* __restrict__ AV, const float* __restrict__ Mask,
                   float* __restrict__ Out)
{
    __shared__ float smem[12288];   // [0..8191]: sK then sAV ; [8192..]: sQ then sS(64x33)
    __shared__ float sBias[32];
    const int b  = blockIdx.y;
    const int p0 = blockIdx.x * 64;
    const int tid = threadIdx.x;
    const int p = tid & 63, lg = tid >> 6;

    {
        const float* kb = K + (size_t)b*CH*AL;
        #pragma unroll
        for (int i=0;i<32;++i) smem[tid + 256*i] = kb[tid + 256*i];
        if (tid < 32) sBias[tid] = 10000.f*Mask[b*AL+tid] - 10000.f;
    }
    float s[8] = {0.f,0.f,0.f,0.f,0.f,0.f,0.f,0.f};
    const float* qb = Q + (size_t)b*CH*HW + p0;
    for (int c0=0; c0<CH; c0+=64){
        __syncthreads();
        #pragma unroll
        for (int i=0;i<4;++i){
            const int cc = (tid>>4) + 16*i;
            const int pp = (tid&15)*4;
            *(float4*)&smem[8192 + cc*64 + pp] = *(const float4*)(qb + (size_t)(c0+cc)*HW + pp);
        }
        __syncthreads();
        for (int cc=0; cc<64; ++cc){
            const float qv = smem[8192 + cc*64 + p];
            const float* kr = &smem[(c0+cc)*32 + lg*8];
            #pragma unroll
            for (int j=0;j<8;++j) s[j] = fmaf(qv, kr[j], s[j]);
        }
    }
    __syncthreads();
    #pragma unroll
    for (int j=0;j<8;++j) smem[8192 + p*33 + lg*8 + j] = s[j]*SCALE + sBias[lg*8+j];
    {   // stage AV over dead sK region (all sK reads completed before barrier above)
        const float* avb = AV + (size_t)b*CH*AL;
        #pragma unroll
        for (int i=0;i<32;++i) smem[tid + 256*i] = avb[tid + 256*i];
    }
    __syncthreads();
    if (tid < 64){
        float* row = &smem[8192 + tid*33];
        float m = row[0];
        #pragma unroll
        for (int l=1;l<32;++l) m = fmaxf(m, row[l]);
        float z = 0.f;
        #pragma unroll
        for (int l=0;l<32;++l){ const float e = expf(row[l]-m); row[l]=e; z+=e; }
        const float rz = 1.f/z;
        #pragma unroll
        for (int l=0;l<32;++l) row[l] *= rz;
    }
    __syncthreads();
    float w[32];
    #pragma unroll
    for (int l=0;l<32;++l) w[l] = smem[8192 + p*33 + l];
    float* ob = Out + (size_t)b*CH*HW + p0 + p;
    for (int ci=0; ci<64; ++ci){
        const int c = lg*64 + ci;
        const float* ar = &smem[c*32];
        float acc = 0.f;
        #pragma unroll
        for (int l=0;l<32;++l) acc = fmaf(w[l], ar[l], acc);
        ob[(size_t)c*HW] = acc;
    }
}

// ---------------------------------------------------------------------------
// Audio attention, phase 1: raw scores Sraw[b][l][p] = scale*sum_c (AQ[b][c][l]*mask[l]) * AK[b][c][p]
// (row-constant mask bias is softmax-invariant over p -> dropped)
__global__ __launch_bounds__(256)
void sima_raw_kernel(const float* __restrict__ AQ, const float* __restrict__ AK,
                     const float* __restrict__ Mask, float* __restrict__ Sraw)
{
    __shared__ float sAQ[CH*AL];
    const int b = blockIdx.y;
    const int p = blockIdx.x*256 + threadIdx.x;
    const int tid = threadIdx.x;
    #pragma unroll
    for (int i=0;i<32;++i){
        const int idx = tid + 256*i;
        sAQ[idx] = AQ[(size_t)b*CH*AL + idx] * Mask[b*AL + (idx&31)] * SCALE;
    }
    __syncthreads();
    float s[32];
    #pragma unroll
    for (int l=0;l<32;++l) s[l]=0.f;
    const float* akb = AK + (size_t)b*CH*HW + p;
    for (int c=0;c<CH;++c){
        const float a = akb[(size_t)c*HW];
        const float* qr = &sAQ[c*32];
        #pragma unroll
        for (int l=0;l<32;++l) s[l] = fmaf(qr[l], a, s[l]);
    }
    float* outp = Sraw + (size_t)b*AL*HW + p;
    #pragma unroll
    for (int l=0;l<32;++l) outp[(size_t)l*HW] = s[l];
}

// Phase 2: per-(b,l) softmax stats over HW. blockIdx.x = b*AL + l.
__global__ __launch_bounds__(256)
void sima_stats_kernel(const float* __restrict__ Sraw, float2* __restrict__ Stats)
{
    const size_t base = (size_t)blockIdx.x * HW;
    const int tid = threadIdx.x;
    float v[16];
    #pragma unroll
    for (int i=0;i<4;++i){
        const float4 t = *(const float4*)(Sraw + base + tid*4 + i*1024);
        v[i*4+0]=t.x; v[i*4+1]=t.y; v[i*4+2]=t.z; v[i*4+3]=t.w;
    }
    float m = v[0];
    #pragma unroll
    for (int i=1;i<16;++i) m = fmaxf(m, v[i]);
    #pragma unroll
    for (int off=1; off<64; off<<=1) m = fmaxf(m, __shfl_xor(m, off));
    __shared__ float rm[4], rz[4];
    if ((tid&63)==0) rm[tid>>6]=m;
    __syncthreads();
    m = fmaxf(fmaxf(rm[0],rm[1]), fmaxf(rm[2],rm[3]));
    float z=0.f;
    #pragma unroll
    for (int i=0;i<16;++i) z += expf(v[i]-m);
    #pragma unroll
    for (int off=1; off<64; off<<=1) z += __shfl_xor(z, off);
    if ((tid&63)==0) rz[tid>>6]=z;
    __syncthreads();
    if (tid==0) Stats[blockIdx.x] = make_float2(m, 1.0f/(rz[0]+rz[1]+rz[2]+rz[3]));
}

// Phase 3: AO[b][c][l] = sum_p softmax(Sraw)[l][p] * VV[b][c][p]  (K=4096 GEMM,
// softmax normalization applied on the fly while staging). blockIdx.x = b*4 + ctile.
__global__ __launch_bounds__(256)
void sima_pv_kernel(const float* __restrict__ Sraw, const float2* __restrict__ Stats,
                    const float* __restrict__ VV, float* __restrict__ AO)
{
    __shared__ float sA[32*33];
    __shared__ float sB[64*36];
    __shared__ float sM[32], sR[32];
    const int b  = blockIdx.x >> 2;
    const int c0 = (blockIdx.x & 3) * 64;
    const int tid = threadIdx.x;
    if (tid < 32){
        const float2 st = Stats[b*AL + tid];
        sM[tid] = st.x; sR[tid] = st.y;
    }
    __syncthreads();
    const int lh = tid & 15;   // l in {lh, lh+16}
    const int cq = tid >> 4;   // c = c0 + cq*4 + j
    const int lr = tid >> 3, k4 = (tid & 7) * 4;
    float acc[2][4] = {{0.f,0.f,0.f,0.f},{0.f,0.f,0.f,0.f}};
    for (int p0=0; p0<HW; p0+=32){
        {
            const float4 t = *(const float4*)(Sraw + ((size_t)b*AL + lr)*HW + p0 + k4);
            const float mm = sM[lr], rr = sR[lr];
            sA[lr*33 + k4+0] = expf(t.x-mm)*rr;
            sA[lr*33 + k4+1] = expf(t.y-mm)*rr;
            sA[lr*33 + k4+2] = expf(t.z-mm)*rr;
            sA[lr*33 + k4+3] = expf(t.w-mm)*rr;
        }
        #pragma unroll
        for (int i=0;i<2;++i){
            const int cc = (tid>>3) + 32*i;
            *(float4*)&sB[cc*36 + k4] = *(const float4*)(VV + ((size_t)b*CH + c0 + cc)*HW + p0 + k4);
        }
        __syncthreads();
        #pragma unroll
        for (int kk=0;kk<32;++kk){
            const float a0 = sA[lh*33 + kk];
            const float a1 = sA[(lh+16)*33 + kk];
            #pragma unroll
            for (int j=0;j<4;++j){
                const float bb = sB[(cq*4+j)*36 + kk];
                acc[0][j] = fmaf(a0, bb, acc[0][j]);
                acc[1][j] = fmaf(a1, bb, acc[1][j]);
            }
        }
        __syncthreads();
    }
    #pragma unroll
    for (int j=0;j<4;++j){
        AO[((size_t)b*CH + c0 + cq*4 + j)*AL + lh]      = acc[0][j];
        AO[((size_t)b*CH + c0 + cq*4 + j)*AL + lh + 16] = acc[1][j];
    }
}

// ---------------------------------------------------------------------------
extern "C" void kernel_launch(void* const* d_in, const int* in_sizes, int n_in,
                              void* d_out, int out_size, void* d_ws, size_t ws_size,
                              hipStream_t stream)
{
    (void)in_sizes; (void)n_in; (void)out_size; (void)ws_size;
    const float* x     = (const float*)d_in[0];
    const float* audio = (const float*)d_in[1];
    const float* amask = (const float*)d_in[2];
    const float* vis_project_w = (const float*)d_in[3];
    const float* vis_project_b = (const float*)d_in[4];
    const float* av_w = (const float*)d_in[5];
    const float* av_b = (const float*)d_in[6];
    const float* vv_w = (const float*)d_in[7];
    const float* vv_b = (const float*)d_in[8];
    const float* vo_w = (const float*)d_in[9];
    const float* vo_b = (const float*)d_in[10];
    const float* ao_w = (const float*)d_in[11];
    const float* ao_b = (const float*)d_in[12];
    const float* vs_key_w = (const float*)d_in[13];
    const float* vs_key_b = (const float*)d_in[14];
    const float* vs_q1_w = (const float*)d_in[15];
    const float* vs_q1_b = (const float*)d_in[16];
    const float* vs_q2_w = (const float*)d_in[17];
    const float* vs_q2_b = (const float*)d_in[18];
    const float* as_key_w = (const float*)d_in[19];
    const float* as_key_b = (const float*)d_in[20];
    const float* as_q1_w = (const float*)d_in[21];
    const float* as_q1_b = (const float*)d_in[22];
    const float* as_q2_w = (const float*)d_in[23];
    const float* as_q2_b = (const float*)d_in[24];
    const float* outconv_w = (const float*)d_in[25];
    const float* outconv_b = (const float*)d_in[26];
    const float* aoc_w = (const float*)d_in[27];
    const float* aoc_b = (const float*)d_in[28];
    const float* gate_w1 = (const float*)d_in[29];
    const float* gate_w2 = (const float*)d_in[30];
    // d_in[31]=vis_weight, d_in[32]=audio_weight: softmax over size-1 == 1.0, unused.

    float* out_x = (float*)d_out;                 // [BT][CH][HW]
    float* out_a = out_x + (size_t)BT*CH*HW;      // [BT][CH][AL]

    float* ws = (float*)d_ws;
    const size_t BIG = (size_t)BT*CH*HW;
    float* B0 = ws;               // vis2 (outconv result)
    float* B1 = ws + BIG;         // q1 / vis_out_raw / vis / ak / g1
    float* B2 = out_x;            // q / vis_out / vv  (d_out x-section as scratch; fully rewritten at end)
    float*  SIMA  = ws + 2*BIG;                                   // [BT][AL][HW]
    float2* STATS = (float2*)(ws + 2*BIG + (size_t)BT*AL*HW);     // [BT*AL]
    float* S0 = (float*)(STATS + BT*AL);          // audio_value [BT][CH][AL]
    float* S1 = S0 + (size_t)BT*CH*AL;            // k
    float* S2 = S1 + (size_t)BT*CH*AL;            // aq
    float* S3 = S2 + (size_t)BT*CH*AL;            // tmp (as_q1 out)
    float* S4 = S3 + (size_t)BT*CH*AL;            // audio_o channel-major
    float* S5 = S4 + (size_t)BT*CH*AL;            // audio_res

    dim3 b256(256);
    dim3 gHW(HW/64, CH/64, BT);
    dim3 gL(BT, CH/8);
    dim3 gAttnV(HW/64, BT);
    dim3 gSimA(HW/256, BT);
    dim3 gNorm(BT*CH);

    // q1 = inorm(conv(vs_q1, x)); q = inorm(conv(vs_q2, q1))
    hipLaunchKernelGGL((conv_hw_kernel<0,0>), gHW, b256, 0, stream, vs_q1_w, vs_q1_b, x, nullptr, B1, nullptr, nullptr);
    hipLaunchKernelGGL(inorm_hw_kernel, gNorm, b256, 0, stream, B1);
    hipLaunchKernelGGL((conv_hw_kernel<0,0>), gHW, b256, 0, stream, vs_q2_w, vs_q2_b, B1, nullptr, B2, nullptr, nullptr);
    hipLaunchKernelGGL(inorm_hw_kernel, gNorm, b256, 0, stream, B2);
    // audio-side small convs
    hipLaunchKernelGGL((conv_l_kernel<1>), gL, b256, 0, stream, av_w, av_b, audio, S0, amask, nullptr);
    hipLaunchKernelGGL((conv_l_kernel<1>), gL, b256, 0, stream, vs_key_w, vs_key_b, audio, S1, amask, nullptr);
    hipLaunchKernelGGL((conv_l_kernel<0>), gL, b256, 0, stream, as_q1_w, as_q1_b, audio, S3, nullptr, nullptr);
    hipLaunchKernelGGL((conv_l_kernel<0>), gL, b256, 0, stream, as_q2_w, as_q2_b, S3, S2, nullptr, nullptr);
    // visual attention -> vis_out_raw (B1); vis_out = inorm(conv(vo, .)) -> B2
    hipLaunchKernelGGL(attn_v_kernel, gAttnV, b256, 0, stream, B2, S1, S0, amask, B1);
    hipLaunchKernelGGL((conv_hw_kernel<0,0>), gHW, b256, 0, stream, vo_w, vo_b, B1, nullptr, B2, nullptr, nullptr);
    hipLaunchKernelGGL(inorm_hw_kernel, gNorm, b256, 0, stream, B2);
    // vis = gelu(conv(vis_project, x)) -> B1 ; vis2 = gelu(conv(outconv, vis*vis_out)) -> B0
    hipLaunchKernelGGL((conv_hw_kernel<0,1>), gHW, b256, 0, stream, vis_project_w, vis_project_b, x, nullptr, B1, nullptr, nullptr);
    hipLaunchKernelGGL((conv_hw_kernel<1,1>), gHW, b256, 0, stream, outconv_w, outconv_b, B1, B2, B0, nullptr, nullptr);
    // ak = inorm(conv(as_key, x)) -> B1 ; raw audio scores + stats
    hipLaunchKernelGGL((conv_hw_kernel<0,0>), gHW, b256, 0, stream, as_key_w, as_key_b, x, nullptr, B1, nullptr, nullptr);
    hipLaunchKernelGGL(inorm_hw_kernel, gNorm, b256, 0, stream, B1);
    hipLaunchKernelGGL(sima_raw_kernel, gSimA, b256, 0, stream, S2, B1, amask, SIMA);
    hipLaunchKernelGGL(sima_stats_kernel, dim3(BT*AL), b256, 0, stream, SIMA, STATS);
    // vis_value = inorm(conv(vv, x)) -> B2 ; audio_o -> S4
    hipLaunchKernelGGL((conv_hw_kernel<0,0>), gHW, b256, 0, stream, vv_w, vv_b, x, nullptr, B2, nullptr, nullptr);
    hipLaunchKernelGGL(inorm_hw_kernel, gNorm, b256, 0, stream, B2);
    hipLaunchKernelGGL(sima_pv_kernel, dim3(BT*4), b256, 0, stream, SIMA, STATS, B2, S4);
    // audio_res = conv(ao, audio_o) ; audio_out = audio + gelu(conv(aoc, audio_res))
    hipLaunchKernelGGL((conv_l_kernel<0>), gL, b256, 0, stream, ao_w, ao_b, S4, S5, nullptr, nullptr);
    hipLaunchKernelGGL((conv_l_kernel<2>), gL, b256, 0, stream, aoc_w, aoc_b, S5, out_a, nullptr, audio);
    // gate path: g1 = relu(conv(gate_w1, vis2)) -> B1 ; x_out = x + tanh(conv(gate_w2, g1))*vis2
    hipLaunchKernelGGL((conv_hw_kernel<0,2>), gHW, b256, 0, stream, gate_w1, nullptr, B0, nullptr, B1, nullptr, nullptr);
    hipLaunchKernelGGL((conv_hw_kernel<0,3>), gHW, b256, 0, stream, gate_w2, nullptr, B1, nullptr, out_x, x, B0);
}

// Round 2
// 3199.078 us; speedup vs baseline: 1.8228x; 1.8228x over previous
//
#include <hip/hip_runtime.h>
#include <math.h>

#define BT 64
#define CH 256
#define HW 4096
#define AL 32
#define SCALE 0.0625f   // 256^-0.5

typedef unsigned short ushort_t;
typedef __bf16 bf16x8 __attribute__((ext_vector_type(8)));
typedef short  short8 __attribute__((ext_vector_type(8)));
typedef float  f32x4  __attribute__((ext_vector_type(4)));

__device__ __forceinline__ float gelu_f(float x){
    return 0.5f*x*(1.0f+erff(x*0.70710678118654752f));
}
__device__ __forceinline__ ushort_t f2bf(float f){
    unsigned int u = __builtin_bit_cast(unsigned int, f);
    u += 0x7fffu + ((u>>16)&1u);
    return (ushort_t)(u>>16);
}
__device__ __forceinline__ float bf2f(ushort_t h){
    unsigned int u = ((unsigned int)h)<<16;
    return __builtin_bit_cast(float, u);
}

#define GLOAD_LDS16(gp, lp) __builtin_amdgcn_global_load_lds( \
    (const __attribute__((address_space(1))) unsigned int*)(gp), \
    (__attribute__((address_space(3))) unsigned int*)(lp), 16, 0, 0)

// ---------------------------------------------------------------------------
// bf16 MFMA GEMM: Out[b][o][p] = epi(sum_c W[o][c]*Xt[b][p][c] + bias[o])
// Wb: bf16 [O][C] (k-contiguous). Xt: bf16 [b][p][c] (k-contiguous).
// 128x128 tile, BK=32, 4 waves, each wave 64x64 via 4x4 of 16x16x32 MFMA.
// EPI: 0=none 1=gelu 2=relu 3=gate: Out = E1 + tanh(v)*E2
// TOUT: 0=fp32 [o][p] ; 1=bf16 transposed [p][o] (with EPI act applied)
template<int EPI, int TOUT>
__global__ __launch_bounds__(256,2)
void gemm_mfma_kernel(const ushort_t* __restrict__ Wb, const float* __restrict__ bias,
                      const ushort_t* __restrict__ Xt, float* __restrict__ Out,
                      ushort_t* __restrict__ OutB,
                      const float* __restrict__ E1, const float* __restrict__ E2)
{
    __shared__ ushort_t sW[128*32];
    __shared__ ushort_t sX[128*32];
    const int b  = blockIdx.z;
    const int o0 = blockIdx.y*128, p0 = blockIdx.x*128;
    const int tid = threadIdx.x, lane = tid & 63, w = tid >> 6;
    const int wm = w >> 1, wn = w & 1;
    const int rr = lane >> 2;          // 0..15 (row within 16-row staging group)
    const int kk8 = (lane & 3) * 8;    // k-offset within 32-wide chunk

    f32x4 acc[4][4] = {};

    for (int k0 = 0; k0 < CH; k0 += 32) {
        #pragma unroll
        for (int j = 0; j < 2; ++j) {
            const ushort_t* gw = Wb + (size_t)(o0 + w*32 + j*16 + rr)*CH + k0 + kk8;
            GLOAD_LDS16(gw, sW + (size_t)w*1024 + j*512);
        }
        #pragma unroll
        for (int j = 0; j < 2; ++j) {
            const ushort_t* gx = Xt + ((size_t)b*HW + p0 + w*32 + j*16 + rr)*CH + k0 + kk8;
            GLOAD_LDS16(gx, sX + (size_t)w*1024 + j*512);
        }
        __syncthreads();
        bf16x8 af[4], bfr[4];
        #pragma unroll
        for (int mt = 0; mt < 4; ++mt) {
            short8 raw = *(const short8*)(sW + (size_t)(wm*64 + mt*16 + (lane&15))*32 + (lane>>4)*8);
            af[mt] = __builtin_bit_cast(bf16x8, raw);
        }
        #pragma unroll
        for (int nt = 0; nt < 4; ++nt) {
            short8 raw = *(const short8*)(sX + (size_t)(wn*64 + nt*16 + (lane&15))*32 + (lane>>4)*8);
            bfr[nt] = __builtin_bit_cast(bf16x8, raw);
        }
        #pragma unroll
        for (int mt = 0; mt < 4; ++mt)
            #pragma unroll
            for (int nt = 0; nt < 4; ++nt)
                acc[mt][nt] = __builtin_amdgcn_mfma_f32_16x16x32_bf16(af[mt], bfr[nt], acc[mt][nt], 0, 0, 0);
        __syncthreads();
    }

    const int pcol = lane & 15, quad = lane >> 4;
    const size_t obase = (size_t)b*CH*HW;
    if (TOUT == 0) {
        #pragma unroll
        for (int mt = 0; mt < 4; ++mt) {
            #pragma unroll
            for (int r = 0; r < 4; ++r) {
                const int o = o0 + wm*64 + mt*16 + quad*4 + r;
                const float bv = bias ? bias[o] : 0.0f;
                #pragma unroll
                for (int nt = 0; nt < 4; ++nt) {
                    const int p = p0 + wn*64 + nt*16 + pcol;
                    float v = acc[mt][nt][r] + bv;
                    if (EPI == 1) v = gelu_f(v);
                    if (EPI == 2) v = fmaxf(v, 0.0f);
                    if (EPI == 3) {
                        const size_t idx = obase + (size_t)o*HW + p;
                        v = E1[idx] + tanhf(v)*E2[idx];
                    }
                    Out[obase + (size_t)o*HW + p] = v;
                }
            }
        }
    } else {
        #pragma unroll
        for (int mt = 0; mt < 4; ++mt) {
            const int ob = o0 + wm*64 + mt*16 + quad*4;
            #pragma unroll
            for (int nt = 0; nt < 4; ++nt) {
                const int p = p0 + wn*64 + nt*16 + pcol;
                ushort4 u;
                float v0 = acc[mt][nt][0] + (bias ? bias[ob+0] : 0.f);
                float v1 = acc[mt][nt][1] + (bias ? bias[ob+1] : 0.f);
                float v2 = acc[mt][nt][2] + (bias ? bias[ob+2] : 0.f);
                float v3 = acc[mt][nt][3] + (bias ? bias[ob+3] : 0.f);
                if (EPI == 1) { v0=gelu_f(v0); v1=gelu_f(v1); v2=gelu_f(v2); v3=gelu_f(v3); }
                if (EPI == 2) { v0=fmaxf(v0,0.f); v1=fmaxf(v1,0.f); v2=fmaxf(v2,0.f); v3=fmaxf(v3,0.f); }
                u.x=f2bf(v0); u.y=f2bf(v1); u.z=f2bf(v2); u.w=f2bf(v3);
                *(ushort4*)(OutB + ((size_t)b*HW + p)*CH + ob) = u;
            }
        }
    }
}

// ---------------------------------------------------------------------------
// Transpose-convert: Xa fp32 [b][c][p] -> Out bf16 [b][p][c].
// MODE 1: multiply by Mul (bf16 [b][p][c]) elementwise before store.
template<int MODE>
__global__ __launch_bounds__(256)
void transpose_bf16_kernel(const float* __restrict__ Xa, const ushort_t* __restrict__ Mul,
                           ushort_t* __restrict__ Out)
{
    __shared__ float sT[32][33];
    const int b = blockIdx.z, c0 = blockIdx.y*32, p0 = blockIdx.x*32;
    const int tid = threadIdx.x;
    {
        const int cr = tid >> 3, pq = (tid & 7)*4;
        const float4 v = *(const float4*)(Xa + ((size_t)b*CH + c0 + cr)*HW + p0 + pq);
        sT[cr][pq+0]=v.x; sT[cr][pq+1]=v.y; sT[cr][pq+2]=v.z; sT[cr][pq+3]=v.w;
    }
    __syncthreads();
    {
        const int pr = tid >> 3, cq = (tid & 7)*4;
        const size_t oidx = ((size_t)b*HW + p0 + pr)*CH + c0 + cq;
        float v0 = sT[cq+0][pr], v1 = sT[cq+1][pr], v2 = sT[cq+2][pr], v3 = sT[cq+3][pr];
        if (MODE == 1) {
            const ushort4 m = *(const ushort4*)(Mul + oidx);
            v0 *= bf2f(m.x); v1 *= bf2f(m.y); v2 *= bf2f(m.z); v3 *= bf2f(m.w);
        }
        ushort4 u; u.x=f2bf(v0); u.y=f2bf(v1); u.z=f2bf(v2); u.w=f2bf(v3);
        *(ushort4*)(Out + oidx) = u;
    }
}

// ---------------------------------------------------------------------------
// Convert 9 weight matrices [256][256] fp32 -> bf16 (same layout). grid(64, 9).
__global__ __launch_bounds__(256)
void wconv_kernel(const float* w0, const float* w1, const float* w2, const float* w3,
                  const float* w4, const float* w5, const float* w6, const float* w7,
                  const float* w8, ushort_t* __restrict__ Wb)
{
    const float* src;
    switch (blockIdx.y) {
        case 0: src=w0; break; case 1: src=w1; break; case 2: src=w2; break;
        case 3: src=w3; break; case 4: src=w4; break; case 5: src=w5; break;
        case 6: src=w6; break; case 7: src=w7; break; default: src=w8; break;
    }
    const int i = (blockIdx.x*256 + threadIdx.x)*4;
    const float4 v = *(const float4*)(src + i);
    ushort4 u; u.x=f2bf(v.x); u.y=f2bf(v.y); u.z=f2bf(v.z); u.w=f2bf(v.w);
    *(ushort4*)(Wb + (size_t)blockIdx.y*65536 + i) = u;
}

// ---------------------------------------------------------------------------
// In-place InstanceNorm over HW per (b,c) row. blockIdx.x = b*CH + c.
__global__ __launch_bounds__(256)
void inorm_hw_kernel(float* __restrict__ Buf)
{
    const size_t base = (size_t)blockIdx.x * HW;
    const int tid = threadIdx.x;
    float4 v[4];
    float s=0.f, ss=0.f;
    #pragma unroll
    for (int i=0;i<4;++i){
        v[i] = *(const float4*)(Buf + base + tid*4 + i*1024);
        s  += v[i].x+v[i].y+v[i].z+v[i].w;
        ss += v[i].x*v[i].x + v[i].y*v[i].y + v[i].z*v[i].z + v[i].w*v[i].w;
    }
    #pragma unroll
    for (int off=1; off<64; off<<=1){
        s  += __shfl_xor(s, off);
        ss += __shfl_xor(ss, off);
    }
    __shared__ float rs[4], rss[4];
    if ((tid&63)==0){ rs[tid>>6]=s; rss[tid>>6]=ss; }
    __syncthreads();
    s  = rs[0]+rs[1]+rs[2]+rs[3];
    ss = rss[0]+rss[1]+rss[2]+rss[3];
    const float mean = s * (1.0f/HW);
    const float var  = ss * (1.0f/HW) - mean*mean;
    const float r = rsqrtf(var + 1e-5f);
    #pragma unroll
    for (int i=0;i<4;++i){
        float4 t;
        t.x=(v[i].x-mean)*r; t.y=(v[i].y-mean)*r; t.z=(v[i].z-mean)*r; t.w=(v[i].w-mean)*r;
        *(float4*)(Buf + base + tid*4 + i*1024) = t;
    }
}

// ---------------------------------------------------------------------------
// Pointwise conv over audio length L. EPI: 0=none, 1=*mask[b][l], 2=Resid + gelu(v)
template<int EPI>
__global__ __launch_bounds__(256)
void conv_l_kernel(const float* __restrict__ W, const float* __restrict__ bias,
                   const float* __restrict__ X, float* __restrict__ Out,
                   const float* __restrict__ Mask, const float* __restrict__ Resid)
{
    const int b = blockIdx.x;
    const int o = blockIdx.y*8 + (threadIdx.x>>5);
    const int l = threadIdx.x & 31;
    const float* xb = X + (size_t)b*CH*AL + l;
    const float* wr = W + (size_t)o*CH;
    float acc = bias ? bias[o] : 0.0f;
    #pragma unroll 8
    for (int c=0;c<CH;++c) acc = fmaf(wr[c], xb[(size_t)c*AL], acc);
    const size_t oi = (size_t)b*CH*AL + (size_t)o*AL + l;
    if (EPI==1) acc *= Mask[b*AL + l];
    if (EPI==2) acc = Resid[oi] + gelu_f(acc);
    Out[oi] = acc;
}

// ---------------------------------------------------------------------------
// Visual attention, fused per 64-token tile (fp32).
__global__ __launch_bounds__(256)
void attn_v_kernel(const float* __restrict__ Q, const float* __restrict__ K,
                   const float* __restrict__ AV, const float* __restrict__ Mask,
                   float* __restrict__ Out)
{
    __shared__ float smem[12288];
    __shared__ float sBias[32];
    const int b  = blockIdx.y;
    const int p0 = blockIdx.x * 64;
    const int tid = threadIdx.x;
    const int p = tid & 63, lg = tid >> 6;

    {
        const float* kb = K + (size_t)b*CH*AL;
        #pragma unroll
        for (int i=0;i<32;++i) smem[tid + 256*i] = kb[tid + 256*i];
        if (tid < 32) sBias[tid] = 10000.f*Mask[b*AL+tid] - 10000.f;
    }
    float s[8] = {0.f,0.f,0.f,0.f,0.f,0.f,0.f,0.f};
    const float* qb = Q + (size_t)b*CH*HW + p0;
    for (int c0=0; c0<CH; c0+=64){
        __syncthreads();
        #pragma unroll
        for (int i=0;i<4;++i){
            const int cc = (tid>>4) + 16*i;
            const int pp = (tid&15)*4;
            *(float4*)&smem[8192 + cc*64 + pp] = *(const float4*)(qb + (size_t)(c0+cc)*HW + pp);
        }
        __syncthreads();
        for (int cc=0; cc<64; ++cc){
            const float qv = smem[8192 + cc*64 + p];
            const float* kr = &smem[(c0+cc)*32 + lg*8];
            #pragma unroll
            for (int j=0;j<8;++j) s[j] = fmaf(qv, kr[j], s[j]);
        }
    }
    __syncthreads();
    #pragma unroll
    for (int j=0;j<8;++j) smem[8192 + p*33 + lg*8 + j] = s[j]*SCALE + sBias[lg*8+j];
    {
        const float* avb = AV + (size_t)b*CH*AL;
        #pragma unroll
        for (int i=0;i<32;++i) smem[tid + 256*i] = avb[tid + 256*i];
    }
    __syncthreads();
    if (tid < 64){
        float* row = &smem[8192 + tid*33];
        float m = row[0];
        #pragma unroll
        for (int l=1;l<32;++l) m = fmaxf(m, row[l]);
        float z = 0.f;
        #pragma unroll
        for (int l=0;l<32;++l){ const float e = expf(row[l]-m); row[l]=e; z+=e; }
        const float rz = 1.f/z;
        #pragma unroll
        for (int l=0;l<32;++l) row[l] *= rz;
    }
    __syncthreads();
    float w[32];
    #pragma unroll
    for (int l=0;l<32;++l) w[l] = smem[8192 + p*33 + l];
    float* ob = Out + (size_t)b*CH*HW + p0 + p;
    for (int ci=0; ci<64; ++ci){
        const int c = lg*64 + ci;
        const float* ar = &smem[c*32];
        float acc = 0.f;
        #pragma unroll
        for (int l=0;l<32;++l) acc = fmaf(w[l], ar[l], acc);
        ob[(size_t)c*HW] = acc;
    }
}

// ---------------------------------------------------------------------------
// Audio attention, phase 1: raw scores.
__global__ __launch_bounds__(256)
void sima_raw_kernel(const float* __restrict__ AQ, const float* __restrict__ AK,
                     const float* __restrict__ Mask, float* __restrict__ Sraw)
{
    __shared__ float sAQ[CH*AL];
    const int b = blockIdx.y;
    const int p = blockIdx.x*256 + threadIdx.x;
    const int tid = threadIdx.x;
    #pragma unroll
    for (int i=0;i<32;++i){
        const int idx = tid + 256*i;
        sAQ[idx] = AQ[(size_t)b*CH*AL + idx] * Mask[b*AL + (idx&31)] * SCALE;
    }
    __syncthreads();
    float s[32];
    #pragma unroll
    for (int l=0;l<32;++l) s[l]=0.f;
    const float* akb = AK + (size_t)b*CH*HW + p;
    for (int c=0;c<CH;++c){
        const float a = akb[(size_t)c*HW];
        const float* qr = &sAQ[c*32];
        #pragma unroll
        for (int l=0;l<32;++l) s[l] = fmaf(qr[l], a, s[l]);
    }
    float* outp = Sraw + (size_t)b*AL*HW + p;
    #pragma unroll
    for (int l=0;l<32;++l) outp[(size_t)l*HW] = s[l];
}

// Phase 2: per-(b,l) softmax stats over HW.
__global__ __launch_bounds__(256)
void sima_stats_kernel(const float* __restrict__ Sraw, float2* __restrict__ Stats)
{
    const size_t base = (size_t)blockIdx.x * HW;
    const int tid = threadIdx.x;
    float v[16];
    #pragma unroll
    for (int i=0;i<4;++i){
        const float4 t = *(const float4*)(Sraw + base + tid*4 + i*1024);
        v[i*4+0]=t.x; v[i*4+1]=t.y; v[i*4+2]=t.z; v[i*4+3]=t.w;
    }
    float m = v[0];
    #pragma unroll
    for (int i=1;i<16;++i) m = fmaxf(m, v[i]);
    #pragma unroll
    for (int off=1; off<64; off<<=1) m = fmaxf(m, __shfl_xor(m, off));
    __shared__ float rm[4], rz[4];
    if ((tid&63)==0) rm[tid>>6]=m;
    __syncthreads();
    m = fmaxf(fmaxf(rm[0],rm[1]), fmaxf(rm[2],rm[3]));
    float z=0.f;
    #pragma unroll
    for (int i=0;i<16;++i) z += expf(v[i]-m);
    #pragma unroll
    for (int off=1; off<64; off<<=1) z += __shfl_xor(z, off);
    if ((tid&63)==0) rz[tid>>6]=z;
    __syncthreads();
    if (tid==0) Stats[blockIdx.x] = make_float2(m, 1.0f/(rz[0]+rz[1]+rz[2]+rz[3]));
}

// Phase 3: AO[b][c][l] = sum_p softmax(Sraw)[l][p] * VV[b][c][p].
__global__ __launch_bounds__(256)
void sima_pv_kernel(const float* __restrict__ Sraw, const float2* __restrict__ Stats,
                    const float* __restrict__ VV, float* __restrict__ AO)
{
    __shared__ float sA[32*33];
    __shared__ float sB[64*36];
    __shared__ float sM[32], sR[32];
    const int b  = blockIdx.x >> 2;
    const int c0 = (blockIdx.x & 3) * 64;
    const int tid = threadIdx.x;
    if (tid < 32){
        const float2 st = Stats[b*AL + tid];
        sM[tid] = st.x; sR[tid] = st.y;
    }
    __syncthreads();
    const int lh = tid & 15;
    const int cq = tid >> 4;
    const int lr = tid >> 3, k4 = (tid & 7) * 4;
    float acc[2][4] = {{0.f,0.f,0.f,0.f},{0.f,0.f,0.f,0.f}};
    for (int p0=0; p0<HW; p0+=32){
        {
            const float4 t = *(const float4*)(Sraw + ((size_t)b*AL + lr)*HW + p0 + k4);
            const float mm = sM[lr], rr2 = sR[lr];
            sA[lr*33 + k4+0] = expf(t.x-mm)*rr2;
            sA[lr*33 + k4+1] = expf(t.y-mm)*rr2;
            sA[lr*33 + k4+2] = expf(t.z-mm)*rr2;
            sA[lr*33 + k4+3] = expf(t.w-mm)*rr2;
        }
        #pragma unroll
        for (int i=0;i<2;++i){
            const int cc = (tid>>3) + 32*i;
            *(float4*)&sB[cc*36 + k4] = *(const float4*)(VV + ((size_t)b*CH + c0 + cc)*HW + p0 + k4);
        }
        __syncthreads();
        #pragma unroll
        for (int kk=0;kk<32;++kk){
            const float a0 = sA[lh*33 + kk];
            const float a1 = sA[(lh+16)*33 + kk];
            #pragma unroll
            for (int j=0;j<4;++j){
                const float bb = sB[(cq*4+j)*36 + kk];
                acc[0][j] = fmaf(a0, bb, acc[0][j]);
                acc[1][j] = fmaf(a1, bb, acc[1][j]);
            }
        }
        __syncthreads();
    }
    #pragma unroll
    for (int j=0;j<4;++j){
        AO[((size_t)b*CH + c0 + cq*4 + j)*AL + lh]      = acc[0][j];
        AO[((size_t)b*CH + c0 + cq*4 + j)*AL + lh + 16] = acc[1][j];
    }
}

// ---------------------------------------------------------------------------
extern "C" void kernel_launch(void* const* d_in, const int* in_sizes, int n_in,
                              void* d_out, int out_size, void* d_ws, size_t ws_size,
                              hipStream_t stream)
{
    (void)in_sizes; (void)n_in; (void)out_size; (void)ws_size;
    const float* x     = (const float*)d_in[0];
    const float* audio = (const float*)d_in[1];
    const float* amask = (const float*)d_in[2];
    const float* vis_project_w = (const float*)d_in[3];
    const float* vis_project_b = (const float*)d_in[4];
    const float* av_w = (const float*)d_in[5];
    const float* av_b = (const float*)d_in[6];
    const float* vv_w = (const float*)d_in[7];
    const float* vv_b = (const float*)d_in[8];
    const float* vo_w = (const float*)d_in[9];
    const float* vo_b = (const float*)d_in[10];
    const float* ao_w = (const float*)d_in[11];
    const float* ao_b = (const float*)d_in[12];
    const float* vs_key_w = (const float*)d_in[13];
    const float* vs_key_b = (const float*)d_in[14];
    const float* vs_q1_w = (const float*)d_in[15];
    const float* vs_q1_b = (const float*)d_in[16];
    const float* vs_q2_w = (const float*)d_in[17];
    const float* vs_q2_b = (const float*)d_in[18];
    const float* as_key_w = (const float*)d_in[19];
    const float* as_key_b = (const float*)d_in[20];
    const float* as_q1_w = (const float*)d_in[21];
    const float* as_q1_b = (const float*)d_in[22];
    const float* as_q2_w = (const float*)d_in[23];
    const float* as_q2_b = (const float*)d_in[24];
    const float* outconv_w = (const float*)d_in[25];
    const float* outconv_b = (const float*)d_in[26];
    const float* aoc_w = (const float*)d_in[27];
    const float* aoc_b = (const float*)d_in[28];
    const float* gate_w1 = (const float*)d_in[29];
    const float* gate_w2 = (const float*)d_in[30];

    float* out_x = (float*)d_out;                 // [BT][CH][HW]
    float* out_a = out_x + (size_t)BT*CH*HW;      // [BT][CH][AL]
    float* B     = out_x;                         // fp32 scratch in d_out x-region

    // ws layout (582.1 MB total; round-1's proven footprint was 583.0 MB)
    const size_t BIG = (size_t)BT*CH*HW;          // 67,108,864 elements
    ushort_t* Xt   = (ushort_t*)d_ws;             // bf16 [b][p][c], 128 MiB
    ushort_t* VISB = Xt + BIG;                    // bf16 vis [b][p][c], 128 MiB
    float*  A     = (float*)(VISB + BIG);         // fp32 [b][c][p], 256 MiB
    float*  SIMA  = A + BIG;                      // fp32 [b][l][p], 32 MiB
    float2* STATS = (float2*)(SIMA + (size_t)BT*AL*HW);
    float*  S0 = (float*)(STATS + BT*AL);         // av  [b][c][l]
    float*  S1 = S0 + (size_t)BT*CH*AL;           // key
    float*  S2 = S1 + (size_t)BT*CH*AL;           // aq
    float*  S3 = S2 + (size_t)BT*CH*AL;           // tmp / audio_res
    float*  S4 = S3 + (size_t)BT*CH*AL;           // audio_o
    ushort_t* Wb = (ushort_t*)(S4 + (size_t)BT*CH*AL);  // 9 bf16 weights

    dim3 b256(256);
    dim3 gW(64, 9);
    dim3 gL(BT, CH/8);
    dim3 gT(HW/32, CH/32, BT);
    dim3 gG(HW/128, CH/128, BT);
    dim3 gNorm(BT*CH);
    dim3 gAttnV(HW/64, BT);
    dim3 gSimA(HW/256, BT);

    #define WSLOT(i) (Wb + (size_t)(i)*65536)
    // slots: 0 vs_q1, 1 as_key, 2 vv, 3 vis_project, 4 vs_q2, 5 vo, 6 outconv, 7 gate_w1, 8 gate_w2
    hipLaunchKernelGGL(wconv_kernel, gW, b256, 0, stream,
                       vs_q1_w, as_key_w, vv_w, vis_project_w, vs_q2_w, vo_w, outconv_w, gate_w1, gate_w2, Wb);
    // audio small convs
    hipLaunchKernelGGL((conv_l_kernel<1>), gL, b256, 0, stream, av_w, av_b, audio, S0, amask, nullptr);
    hipLaunchKernelGGL((conv_l_kernel<1>), gL, b256, 0, stream, vs_key_w, vs_key_b, audio, S1, amask, nullptr);
    hipLaunchKernelGGL((conv_l_kernel<0>), gL, b256, 0, stream, as_q1_w, as_q1_b, audio, S3, nullptr, nullptr);
    hipLaunchKernelGGL((conv_l_kernel<0>), gL, b256, 0, stream, as_q2_w, as_q2_b, S3, S2, nullptr, nullptr);
    // Xt = T(x); 4 convs on x
    hipLaunchKernelGGL((transpose_bf16_kernel<0>), gT, b256, 0, stream, x, nullptr, Xt);
    hipLaunchKernelGGL((gemm_mfma_kernel<0,0>), gG, b256, 0, stream, WSLOT(0), vs_q1_b, Xt, A, nullptr, nullptr, nullptr);
    hipLaunchKernelGGL(inorm_hw_kernel, gNorm, b256, 0, stream, A);            // q1n in A
    hipLaunchKernelGGL((gemm_mfma_kernel<0,0>), gG, b256, 0, stream, WSLOT(1), as_key_b, Xt, B, nullptr, nullptr, nullptr);
    hipLaunchKernelGGL(inorm_hw_kernel, gNorm, b256, 0, stream, B);            // ak in B
    hipLaunchKernelGGL(sima_raw_kernel, gSimA, b256, 0, stream, S2, B, amask, SIMA);
    hipLaunchKernelGGL(sima_stats_kernel, dim3(BT*AL), b256, 0, stream, SIMA, STATS);
    hipLaunchKernelGGL((gemm_mfma_kernel<0,0>), gG, b256, 0, stream, WSLOT(2), vv_b, Xt, B, nullptr, nullptr, nullptr);
    hipLaunchKernelGGL(inorm_hw_kernel, gNorm, b256, 0, stream, B);            // vv in B
    hipLaunchKernelGGL(sima_pv_kernel, dim3(BT*4), b256, 0, stream, SIMA, STATS, B, S4);
    hipLaunchKernelGGL((conv_l_kernel<0>), gL, b256, 0, stream, ao_w, ao_b, S4, S3, nullptr, nullptr);
    hipLaunchKernelGGL((conv_l_kernel<2>), gL, b256, 0, stream, aoc_w, aoc_b, S3, out_a, nullptr, audio);
    hipLaunchKernelGGL((gemm_mfma_kernel<1,1>), gG, b256, 0, stream, WSLOT(3), vis_project_b, Xt, nullptr, VISB, nullptr, nullptr);
    // q = inorm(conv(vs_q2, q1n))
    hipLaunchKernelGGL((transpose_bf16_kernel<0>), gT, b256, 0, stream, A, nullptr, Xt);
    hipLaunchKernelGGL((gemm_mfma_kernel<0,0>), gG, b256, 0, stream, WSLOT(4), vs_q2_b, Xt, B, nullptr, nullptr, nullptr);
    hipLaunchKernelGGL(inorm_hw_kernel, gNorm, b256, 0, stream, B);            // q in B
    hipLaunchKernelGGL(attn_v_kernel, gAttnV, b256, 0, stream, B, S1, S0, amask, A);   // vo_in in A
    hipLaunchKernelGGL((transpose_bf16_kernel<0>), gT, b256, 0, stream, A, nullptr, Xt);
    hipLaunchKernelGGL((gemm_mfma_kernel<0,0>), gG, b256, 0, stream, WSLOT(5), vo_b, Xt, B, nullptr, nullptr, nullptr);
    hipLaunchKernelGGL(inorm_hw_kernel, gNorm, b256, 0, stream, B);            // vis_out in B
    // Xt = bf(vis_out * vis); vis2 = gelu(conv(outconv, Xt)) -> A
    hipLaunchKernelGGL((transpose_bf16_kernel<1>), gT, b256, 0, stream, B, VISB, Xt);
    hipLaunchKernelGGL((gemm_mfma_kernel<1,0>), gG, b256, 0, stream, WSLOT(6), outconv_b, Xt, A, nullptr, nullptr, nullptr);
    // gate path
    hipLaunchKernelGGL((transpose_bf16_kernel<0>), gT, b256, 0, stream, A, nullptr, Xt);
    hipLaunchKernelGGL((gemm_mfma_kernel<2,0>), gG, b256, 0, stream, WSLOT(7), nullptr, Xt, B, nullptr, nullptr, nullptr);
    hipLaunchKernelGGL((transpose_bf16_kernel<0>), gT, b256, 0, stream, B, nullptr, Xt);
    hipLaunchKernelGGL((gemm_mfma_kernel<3,0>), gG, b256, 0, stream, WSLOT(8), nullptr, Xt, out_x, nullptr, x, A);
    #undef WSLOT
}